// Round 1
// baseline (2643.200 us; speedup 1.0000x reference)
//
#include <hip/hip_runtime.h>

// TernaryLinear: out[8192,11008] = x[8192,4096] @ (w*scales_grouped)[11008,4096]^T + bias
// bf16 MFMA path: ternary w exact in bf16; x and w*s round at 2^-9 -> abs err ~0.1 << 3.68 thr.

#define OUT_F   11008
#define IN_F    4096
#define TOKENS  8192
#define NGROUPS 32

#define BM 128
#define BN 128
#define BK 32
#define LDS_STRIDE 40   // 32 + 8 pad: rows are 80B (16B-aligned), bank aliasing <= 2-way (free)

typedef __attribute__((ext_vector_type(8))) short  short8;  // 8 bf16 = 4 VGPRs (MFMA A/B frag)
typedef __attribute__((ext_vector_type(4))) float  f32x4;   // MFMA C/D frag

__device__ __forceinline__ unsigned short f2bf(float f) {
    union { float f; unsigned u; } v; v.f = f;
    unsigned r = v.u + 0x7FFFu + ((v.u >> 16) & 1u);   // RNE
    return (unsigned short)(r >> 16);
}

__global__ __launch_bounds__(256, 2)
void ternary_gemm(const float* __restrict__ x,
                  const float* __restrict__ w,
                  const float* __restrict__ scales,
                  const float* __restrict__ bias,
                  float* __restrict__ out) {
    __shared__ unsigned short As[BM * LDS_STRIDE];
    __shared__ unsigned short Bs[BN * LDS_STRIDE];

    const int tid  = threadIdx.x;
    const int lane = tid & 63;
    const int wave = tid >> 6;
    const int wm   = (wave & 1) * 64;   // wave's m-offset within 128-tile
    const int wn   = (wave >> 1) * 64;  // wave's n-offset
    const int q    = lane >> 4;         // quad 0..3
    const int r    = lane & 15;

    const int n0 = blockIdx.x * BN;
    const int m0 = blockIdx.y * BM;

    // staging: 8 threads/row * 4 floats, 32 rows per step, 4 steps -> 128x32 tile
    const int srow = tid >> 3;        // 0..31
    const int scol = (tid & 7) * 4;   // 0..28

    f32x4 acc[4][4];
    const f32x4 zero = {0.0f, 0.0f, 0.0f, 0.0f};
    #pragma unroll
    for (int i = 0; i < 4; ++i)
        #pragma unroll
        for (int j = 0; j < 4; ++j)
            acc[i][j] = zero;

    float biasv[4];
    #pragma unroll
    for (int ni = 0; ni < 4; ++ni)
        biasv[ni] = bias[n0 + wn + ni * 16 + r];

    for (int kt = 0; kt < IN_F / BK; ++kt) {
        const int k0 = kt * BK;
        const int g  = k0 >> 7;   // 128-wide groups: uniform per K-tile (k0%128 + 28 < 128)

        // global loads into registers (before the barrier so they overlap prior compute)
        float4 a4[4], b4[4];
        float  sc[4];
        #pragma unroll
        for (int s = 0; s < 4; ++s) {
            const int row = s * 32 + srow;
            a4[s] = *(const float4*)(x + (size_t)(m0 + row) * IN_F + k0 + scol);
            b4[s] = *(const float4*)(w + (size_t)(n0 + row) * IN_F + k0 + scol);
            sc[s] = scales[(n0 + row) * NGROUPS + g];
        }

        __syncthreads();   // previous iteration's frag reads done
        #pragma unroll
        for (int s = 0; s < 4; ++s) {
            const int row = s * 32 + srow;
            ushort4 av, bv;
            av.x = f2bf(a4[s].x);          av.y = f2bf(a4[s].y);
            av.z = f2bf(a4[s].z);          av.w = f2bf(a4[s].w);
            bv.x = f2bf(b4[s].x * sc[s]);  bv.y = f2bf(b4[s].y * sc[s]);
            bv.z = f2bf(b4[s].z * sc[s]);  bv.w = f2bf(b4[s].w * sc[s]);
            *(ushort4*)(As + row * LDS_STRIDE + scol) = av;
            *(ushort4*)(Bs + row * LDS_STRIDE + scol) = bv;
        }
        __syncthreads();   // tile staged

        // LDS -> frags: A[m=lane&15][k=quad*8+j], B (from B^T layout) Bs[n=lane&15][k=quad*8+j]
        short8 af[4], bf[4];
        #pragma unroll
        for (int mi = 0; mi < 4; ++mi)
            af[mi] = *(const short8*)(As + (wm + mi * 16 + r) * LDS_STRIDE + q * 8);
        #pragma unroll
        for (int ni = 0; ni < 4; ++ni)
            bf[ni] = *(const short8*)(Bs + (wn + ni * 16 + r) * LDS_STRIDE + q * 8);

        #pragma unroll
        for (int mi = 0; mi < 4; ++mi)
            #pragma unroll
            for (int ni = 0; ni < 4; ++ni)
                acc[mi][ni] = __builtin_amdgcn_mfma_f32_16x16x32_bf16(
                    af[mi], bf[ni], acc[mi][ni], 0, 0, 0);
    }

    // epilogue: C/D layout col=lane&15, row=quad*4+reg (m89-verified); bias per col
    #pragma unroll
    for (int mi = 0; mi < 4; ++mi) {
        const int row0 = m0 + wm + mi * 16 + q * 4;
        #pragma unroll
        for (int ni = 0; ni < 4; ++ni) {
            const int col = n0 + wn + ni * 16 + r;
            const float bv = biasv[ni];
            #pragma unroll
            for (int e = 0; e < 4; ++e)
                out[(size_t)(row0 + e) * OUT_F + col] = acc[mi][ni][e] + bv;
        }
    }
}

extern "C" void kernel_launch(void* const* d_in, const int* in_sizes, int n_in,
                              void* d_out, int out_size, void* d_ws, size_t ws_size,
                              hipStream_t stream) {
    const float* x      = (const float*)d_in[0];
    const float* w      = (const float*)d_in[1];
    const float* scales = (const float*)d_in[2];
    const float* bias   = (const float*)d_in[3];
    float* out          = (float*)d_out;

    dim3 grid(OUT_F / BN, TOKENS / BM);   // 86 x 64 = 5504 blocks
    ternary_gemm<<<grid, 256, 0, stream>>>(x, w, scales, bias, out);
}

// Round 2
// 1792.905 us; speedup vs baseline: 1.4743x; 1.4743x over previous
//
#include <hip/hip_runtime.h>

// TernaryLinear: out[8192,11008] = x[8192,4096] @ (w*scales_grouped)[11008,4096]^T + bias
// R2: pre-convert x and dequantized W to bf16 in workspace (154 MB, fits L3),
// then m97-style MFMA GEMM with global_load_lds width-16 staging.

#define OUT_F   11008
#define IN_F    4096
#define TOKENS  8192
#define NGROUPS 32

#define BM 128
#define BN 128
#define BK 32

typedef __attribute__((ext_vector_type(8))) short  short8;  // 8 bf16 = 4 VGPRs
typedef __attribute__((ext_vector_type(4))) float  f32x4;

__device__ __forceinline__ unsigned short f2bf(float f) {
    union { float f; unsigned u; } v; v.f = f;
    unsigned r = v.u + 0x7FFFu + ((v.u >> 16) & 1u);   // RNE
    return (unsigned short)(r >> 16);
}

__device__ __forceinline__ void load_lds16(const void* g, void* l) {
    // lane i's 16B -> lds_base + i*16 (wave-uniform LDS base, per-lane global addr)
    __builtin_amdgcn_global_load_lds(
        (const __attribute__((address_space(1))) unsigned int*)g,
        (__attribute__((address_space(3))) unsigned int*)l, 16, 0, 0);
}

// ---- conversion pass 1: x fp32 -> bf16 -------------------------------------
__global__ __launch_bounds__(256)
void cvt_x(const float* __restrict__ x, unsigned short* __restrict__ xb) {
    size_t i = ((size_t)blockIdx.x * 256 + threadIdx.x) * 4;
    float4 v = *(const float4*)(x + i);
    ushort4 o;
    o.x = f2bf(v.x); o.y = f2bf(v.y); o.z = f2bf(v.z); o.w = f2bf(v.w);
    *(ushort4*)(xb + i) = o;
}

// ---- conversion pass 2: W dequant (ternary * group scale) -> bf16 ----------
__global__ __launch_bounds__(256)
void cvt_w(const float* __restrict__ w, const float* __restrict__ scales,
           unsigned short* __restrict__ wb) {
    size_t i = ((size_t)blockIdx.x * 256 + threadIdx.x) * 4;
    int o = (int)(i >> 12);          // / IN_F
    int k = (int)(i & (IN_F - 1));
    float s = scales[(o << 5) + (k >> 7)];
    float4 v = *(const float4*)(w + i);
    ushort4 q;
    q.x = f2bf(v.x * s); q.y = f2bf(v.y * s);
    q.z = f2bf(v.z * s); q.w = f2bf(v.w * s);
    *(ushort4*)(wb + i) = q;
}

// ---- main GEMM: bf16 inputs, m97 structure ---------------------------------
__global__ __launch_bounds__(256, 2)
void gemm_bf16(const unsigned short* __restrict__ xb,
               const unsigned short* __restrict__ wb,
               const float* __restrict__ bias,
               float* __restrict__ out) {
    __shared__ unsigned short As[BM * BK];   // 8 KB, row-major stride 32, NO pad
    __shared__ unsigned short Bs[BN * BK];   // (layout forced by global_load_lds)

    const int tid  = threadIdx.x;
    const int lane = tid & 63;
    const int wave = tid >> 6;
    const int wm   = (wave & 1) * 64;
    const int wn   = (wave >> 1) * 64;
    const int q    = lane >> 4;
    const int r    = lane & 15;

    const int n0 = blockIdx.x * BN;
    const int m0 = blockIdx.y * BM;

    // staging: wave handles rows [wave*32, wave*32+32) of each 128x32 tile.
    // lane i -> row wave*32 + (i>>2), k-segment (i&3)*8 elements; LDS lands at
    // wave-chunk base + i*16 B == row-major (row*32 + seg*8) exactly.
    const int crow = lane >> 2;          // 0..15
    const int cseg = (lane & 3) * 8;     // 0..24 elements
    const size_t gA = (size_t)(m0 + wave * 32 + crow) * IN_F + cseg;
    const size_t gB = (size_t)(n0 + wave * 32 + crow) * IN_F + cseg;
    unsigned short* lA = As + wave * 1024;       // 2 chunks of 512 elems
    unsigned short* lB = Bs + wave * 1024;

    f32x4 acc[4][4];
    const f32x4 zero = {0.0f, 0.0f, 0.0f, 0.0f};
    #pragma unroll
    for (int i = 0; i < 4; ++i)
        #pragma unroll
        for (int j = 0; j < 4; ++j)
            acc[i][j] = zero;

    float biasv[4];
    #pragma unroll
    for (int ni = 0; ni < 4; ++ni)
        biasv[ni] = bias[n0 + wn + ni * 16 + r];

    for (int kt = 0; kt < IN_F / BK; ++kt) {
        const int k0 = kt * BK;

        __syncthreads();   // all waves done reading previous tile
        load_lds16(xb + gA + k0,                lA);        // rows wave*32..+15
        load_lds16(xb + gA + k0 + 16 * IN_F,    lA + 512);  // rows +16..+31
        load_lds16(wb + gB + k0,                lB);
        load_lds16(wb + gB + k0 + 16 * IN_F,    lB + 512);
        __syncthreads();   // vmcnt drained: tile fully staged

        short8 af[4], bf[4];
        #pragma unroll
        for (int mi = 0; mi < 4; ++mi)
            af[mi] = *(const short8*)(As + (wm + mi * 16 + r) * BK + q * 8);
        #pragma unroll
        for (int ni = 0; ni < 4; ++ni)
            bf[ni] = *(const short8*)(Bs + (wn + ni * 16 + r) * BK + q * 8);

        #pragma unroll
        for (int mi = 0; mi < 4; ++mi)
            #pragma unroll
            for (int ni = 0; ni < 4; ++ni)
                acc[mi][ni] = __builtin_amdgcn_mfma_f32_16x16x32_bf16(
                    af[mi], bf[ni], acc[mi][ni], 0, 0, 0);
    }

    // epilogue: C/D layout col=lane&15, row=quad*4+reg (verified in R1)
    #pragma unroll
    for (int mi = 0; mi < 4; ++mi) {
        const int row0 = m0 + wm + mi * 16 + q * 4;
        #pragma unroll
        for (int ni = 0; ni < 4; ++ni) {
            const int col = n0 + wn + ni * 16 + r;
            const float bv = biasv[ni];
            #pragma unroll
            for (int e = 0; e < 4; ++e)
                out[(size_t)(row0 + e) * OUT_F + col] = acc[mi][ni][e] + bv;
        }
    }
}

// ---- fallback (round-1 fused kernel) if workspace too small ----------------
#define LDS_STRIDE 40
__global__ __launch_bounds__(256, 2)
void ternary_gemm_fused(const float* __restrict__ x,
                        const float* __restrict__ w,
                        const float* __restrict__ scales,
                        const float* __restrict__ bias,
                        float* __restrict__ out) {
    __shared__ unsigned short As[BM * LDS_STRIDE];
    __shared__ unsigned short Bs[BN * LDS_STRIDE];

    const int tid  = threadIdx.x;
    const int lane = tid & 63;
    const int wave = tid >> 6;
    const int wm   = (wave & 1) * 64;
    const int wn   = (wave >> 1) * 64;
    const int q    = lane >> 4;
    const int r    = lane & 15;
    const int n0 = blockIdx.x * BN;
    const int m0 = blockIdx.y * BM;
    const int srow = tid >> 3;
    const int scol = (tid & 7) * 4;

    f32x4 acc[4][4];
    const f32x4 zero = {0.0f, 0.0f, 0.0f, 0.0f};
    #pragma unroll
    for (int i = 0; i < 4; ++i)
        #pragma unroll
        for (int j = 0; j < 4; ++j)
            acc[i][j] = zero;

    float biasv[4];
    #pragma unroll
    for (int ni = 0; ni < 4; ++ni)
        biasv[ni] = bias[n0 + wn + ni * 16 + r];

    for (int kt = 0; kt < IN_F / BK; ++kt) {
        const int k0 = kt * BK;
        const int g  = k0 >> 7;
        float4 a4[4], b4[4];
        float  sc[4];
        #pragma unroll
        for (int s = 0; s < 4; ++s) {
            const int row = s * 32 + srow;
            a4[s] = *(const float4*)(x + (size_t)(m0 + row) * IN_F + k0 + scol);
            b4[s] = *(const float4*)(w + (size_t)(n0 + row) * IN_F + k0 + scol);
            sc[s] = scales[(n0 + row) * NGROUPS + g];
        }
        __syncthreads();
        #pragma unroll
        for (int s = 0; s < 4; ++s) {
            const int row = s * 32 + srow;
            ushort4 av, bv;
            av.x = f2bf(a4[s].x);          av.y = f2bf(a4[s].y);
            av.z = f2bf(a4[s].z);          av.w = f2bf(a4[s].w);
            bv.x = f2bf(b4[s].x * sc[s]);  bv.y = f2bf(b4[s].y * sc[s]);
            bv.z = f2bf(b4[s].z * sc[s]);  bv.w = f2bf(b4[s].w * sc[s]);
            *(ushort4*)(As + row * LDS_STRIDE + scol) = av;
            *(ushort4*)(Bs + row * LDS_STRIDE + scol) = bv;
        }
        __syncthreads();
        short8 af[4], bf[4];
        #pragma unroll
        for (int mi = 0; mi < 4; ++mi)
            af[mi] = *(const short8*)(As + (wm + mi * 16 + r) * LDS_STRIDE + q * 8);
        #pragma unroll
        for (int ni = 0; ni < 4; ++ni)
            bf[ni] = *(const short8*)(Bs + (wn + ni * 16 + r) * LDS_STRIDE + q * 8);
        #pragma unroll
        for (int mi = 0; mi < 4; ++mi)
            #pragma unroll
            for (int ni = 0; ni < 4; ++ni)
                acc[mi][ni] = __builtin_amdgcn_mfma_f32_16x16x32_bf16(
                    af[mi], bf[ni], acc[mi][ni], 0, 0, 0);
    }
    #pragma unroll
    for (int mi = 0; mi < 4; ++mi) {
        const int row0 = m0 + wm + mi * 16 + q * 4;
        #pragma unroll
        for (int ni = 0; ni < 4; ++ni) {
            const int col = n0 + wn + ni * 16 + r;
            const float bv = biasv[ni];
            #pragma unroll
            for (int e = 0; e < 4; ++e)
                out[(size_t)(row0 + e) * OUT_F + col] = acc[mi][ni][e] + bv;
        }
    }
}

extern "C" void kernel_launch(void* const* d_in, const int* in_sizes, int n_in,
                              void* d_out, int out_size, void* d_ws, size_t ws_size,
                              hipStream_t stream) {
    const float* x      = (const float*)d_in[0];
    const float* w      = (const float*)d_in[1];
    const float* scales = (const float*)d_in[2];
    const float* bias   = (const float*)d_in[3];
    float* out          = (float*)d_out;

    const size_t xb_elems = (size_t)TOKENS * IN_F;           // 33.5M
    const size_t wb_elems = (size_t)OUT_F * IN_F;            // 45.1M
    const size_t need = (xb_elems + wb_elems) * sizeof(unsigned short);  // ~157 MB

    dim3 grid(OUT_F / BN, TOKENS / BM);   // 86 x 64

    if (ws_size >= need) {
        unsigned short* xb = (unsigned short*)d_ws;
        unsigned short* wb = xb + xb_elems;
        cvt_x<<<(int)(xb_elems / 1024), 256, 0, stream>>>(x, xb);
        cvt_w<<<(int)(wb_elems / 1024), 256, 0, stream>>>(w, scales, wb);
        gemm_bf16<<<grid, 256, 0, stream>>>(xb, wb, bias, out);
    } else {
        ternary_gemm_fused<<<grid, 256, 0, stream>>>(x, w, scales, bias, out);
    }
}